// Round 1
// baseline (995.763 us; speedup 1.0000x reference)
//
#include <hip/hip_runtime.h>

#define NTOKEN 200000
#define NINP   64
#define NEDGE  2000000
#define NBL    12800   // B*L = 64*200

// ---------------- degree / norm ----------------
__global__ void k_init_deg(float* __restrict__ deg) {
    int i = blockIdx.x * blockDim.x + threadIdx.x;
    if (i < NTOKEN) deg[i] = 1.0f;   // self-loop
}

__global__ void k_deg(const int* __restrict__ dst, float* __restrict__ deg) {
    int e = blockIdx.x * blockDim.x + threadIdx.x;
    if (e < NEDGE) atomicAdd(&deg[dst[e]], 1.0f);
}

__global__ void k_rsqrt(float* __restrict__ deg) {
    int i = blockIdx.x * blockDim.x + threadIdx.x;
    if (i < NTOKEN) deg[i] = rsqrtf(deg[i]);
}

// ---------------- layer 1: P1 = A @ emb ----------------
// self-loop contribution: P1[i,f] = dinv[i]^2 * emb[i,f]
__global__ void k_selfloop1(const float* __restrict__ emb, const float* __restrict__ dinv,
                            float* __restrict__ P1) {
    int id = blockIdx.x * blockDim.x + threadIdx.x;
    if (id < NTOKEN * NINP) {
        int node = id >> 6;
        float d = dinv[node];
        P1[id] = d * d * emb[id];
    }
}

// one wave (64 lanes) per edge, lane = feature
__global__ void k_scatter1(const int* __restrict__ src, const int* __restrict__ dst,
                           const float* __restrict__ dinv, const float* __restrict__ emb,
                           float* __restrict__ P1) {
    int e = blockIdx.x * 4 + (threadIdx.x >> 6);
    if (e >= NEDGE) return;
    int lane = threadIdx.x & 63;
    int s = src[e], d = dst[e];
    float w = dinv[s] * dinv[d];
    atomicAdd(&P1[d * NINP + lane], w * emb[s * NINP + lane]);
}

// ---------------- mark queried nodes, compact relevant edges ----------------
__global__ void k_zero_mark(unsigned char* __restrict__ mark, int* __restrict__ counter) {
    int i = blockIdx.x * blockDim.x + threadIdx.x;
    if (i < NTOKEN) mark[i] = 0;
    if (i == 0) *counter = 0;
}

__global__ void k_mark(const int* __restrict__ inp, unsigned char* __restrict__ mark) {
    int t = blockIdx.x * blockDim.x + threadIdx.x;
    if (t < NBL) mark[inp[t]] = 1;
}

__global__ void k_compact(const int* __restrict__ dst, const unsigned char* __restrict__ mark,
                          int* __restrict__ elist, int* __restrict__ counter) {
    int e = blockIdx.x * blockDim.x + threadIdx.x;
    if (e < NEDGE && mark[dst[e]]) {
        int idx = atomicAdd(counter, 1);
        elist[idx] = e;
    }
}

// ---------------- layer 2 (marked nodes only): P2 = A @ P1, s = rowsum helper ----------------
__global__ void k_selfloop2(const float* __restrict__ P1, const float* __restrict__ dinv,
                            const unsigned char* __restrict__ mark,
                            float* __restrict__ P2, float* __restrict__ sArr) {
    int id = blockIdx.x * blockDim.x + threadIdx.x;
    if (id >= NTOKEN * NINP) return;
    int node = id >> 6;
    if (!mark[node]) return;
    float d = dinv[node];
    P2[id] = d * d * P1[id];
    if ((id & 63) == 0) sArr[node] = d;   // self-loop part of row-sum
}

// grid-stride over compacted edge list, one wave per edge
__global__ void k_scatter2(const int* __restrict__ src, const int* __restrict__ dst,
                           const int* __restrict__ elist, const int* __restrict__ counter,
                           const float* __restrict__ dinv, const float* __restrict__ P1,
                           float* __restrict__ P2, float* __restrict__ sArr) {
    int n = *counter;
    int wid = blockIdx.x * (blockDim.x >> 6) + (threadIdx.x >> 6);
    int nw  = gridDim.x * (blockDim.x >> 6);
    int lane = threadIdx.x & 63;
    for (int i = wid; i < n; i += nw) {
        int e = elist[i];
        int sN = src[e], d = dst[e];
        float ds = dinv[sN];
        float w = ds * dinv[d];
        atomicAdd(&P2[d * NINP + lane], w * P1[sN * NINP + lane]);
        if (lane == 0) atomicAdd(&sArr[d], ds);
    }
}

// ---------------- fold weights: W12 = W1@W2 (64x64), bb = b1@W2 (64) ----------------
__global__ void k_w12(const float* __restrict__ W1, const float* __restrict__ W2,
                      const float* __restrict__ b1, float* __restrict__ W12,
                      float* __restrict__ bb) {
    int id = blockIdx.x * blockDim.x + threadIdx.x;
    if (id < 64 * 64) {
        int i = id >> 6, j = id & 63;
        float acc = 0.f;
        for (int k = 0; k < 128; ++k) acc += W1[i * 128 + k] * W2[k * 64 + j];
        W12[id] = acc;
    } else if (id < 64 * 64 + 64) {
        int j = id - 64 * 64;
        float acc = 0.f;
        for (int k = 0; k < 128; ++k) acc += b1[k] * W2[k * 64 + j];
        bb[j] = acc;
    }
}

// ---------------- gather + tiny GEMM + biases ----------------
// out[t,f] = sum_k P2[node,k]*W12[k,f] + dinv[node]*s[node]*bb[f] + b2[f]
__global__ void k_final(const int* __restrict__ inp, const float* __restrict__ P2,
                        const float* __restrict__ dinv, const float* __restrict__ sArr,
                        const float* __restrict__ W12, const float* __restrict__ bb,
                        const float* __restrict__ b2, float* __restrict__ out) {
    int t = blockIdx.x * 4 + (threadIdx.x >> 6);
    if (t >= NBL) return;
    int f = threadIdx.x & 63;
    int node = inp[t];
    float acc = b2[f] + dinv[node] * sArr[node] * bb[f];
    const float* row = &P2[node * NINP];
#pragma unroll
    for (int k = 0; k < 64; ++k) acc += row[k] * W12[k * 64 + f];
    out[t * 64 + f] = acc;
}

extern "C" void kernel_launch(void* const* d_in, const int* in_sizes, int n_in,
                              void* d_out, int out_size, void* d_ws, size_t ws_size,
                              hipStream_t stream) {
    const int*   inp  = (const int*)d_in[0];
    // d_in[1] input_timestamp, d_in[2] input_id: unused by the reference
    const int*   eidx = (const int*)d_in[3];
    const int*   esrc = eidx;
    const int*   edst = eidx + NEDGE;
    const float* emb  = (const float*)d_in[4];
    const float* W1   = (const float*)d_in[5];
    const float* b1   = (const float*)d_in[6];
    const float* W2   = (const float*)d_in[7];
    const float* b2   = (const float*)d_in[8];
    float* out = (float*)d_out;

    char* ws = (char*)d_ws;
    float*         dinv    = (float*)(ws + 0);          // 800000 B
    float*         sArr    = (float*)(ws + 800256);     // 800000 B
    unsigned char* mark    = (unsigned char*)(ws + 1600512);  // 200000 B
    int*           counter = (int*)(ws + 1800704);      // 4 B
    int*           elist   = (int*)(ws + 1800960);      // 8 MB worst case
    float*         W12     = (float*)(ws + 9801216);    // 16 KB
    float*         bb      = (float*)(ws + 9817600);    // 256 B
    float*         P1      = (float*)(ws + 9817856);    // 51.2 MB
    float*         P2      = (float*)(ws + 61017856);   // 51.2 MB

    const int B = 256;

    k_init_deg<<<(NTOKEN + B - 1) / B, B, 0, stream>>>(dinv);
    k_deg<<<(NEDGE + B - 1) / B, B, 0, stream>>>(edst, dinv);
    k_rsqrt<<<(NTOKEN + B - 1) / B, B, 0, stream>>>(dinv);

    k_selfloop1<<<(NTOKEN * NINP + B - 1) / B, B, 0, stream>>>(emb, dinv, P1);
    k_scatter1<<<(NEDGE + 3) / 4, B, 0, stream>>>(esrc, edst, dinv, emb, P1);

    k_zero_mark<<<(NTOKEN + B - 1) / B, B, 0, stream>>>(mark, counter);
    k_mark<<<(NBL + B - 1) / B, B, 0, stream>>>(inp, mark);
    k_compact<<<(NEDGE + B - 1) / B, B, 0, stream>>>(edst, mark, elist, counter);

    k_selfloop2<<<(NTOKEN * NINP + B - 1) / B, B, 0, stream>>>(P1, dinv, mark, P2, sArr);
    k_scatter2<<<2048, B, 0, stream>>>(esrc, edst, elist, counter, dinv, P1, P2, sArr);

    k_w12<<<(64 * 64 + 64 + B - 1) / B, B, 0, stream>>>(W1, W2, b1, W12, bb);
    k_final<<<(NBL + 3) / 4, B, 0, stream>>>(inp, P2, dinv, sArr, W12, bb, b2, out);
}

// Round 2
// 408.362 us; speedup vs baseline: 2.4384x; 2.4384x over previous
//
#include <hip/hip_runtime.h>

#define NTOKEN 200000
#define NINP   64
#define NEDGE  2000000
#define NBL    12800          // B*L
#define NB1    ((NTOKEN + 255) / 256)   // 782 blocks for node-wide scans

// ---------- init: zero counters / flags ----------
__global__ void k_init(int* __restrict__ cdeg, unsigned char* __restrict__ mark,
                       unsigned char* __restrict__ need2) {
    int i = blockIdx.x * blockDim.x + threadIdx.x;
    if (i < NTOKEN) { cdeg[i] = 0; mark[i] = 0; need2[i] = 0; }
}

// ---------- degree count (int atomics) ----------
__global__ void k_count(const int* __restrict__ dst, int* __restrict__ cdeg) {
    int e = blockIdx.x * blockDim.x + threadIdx.x;
    if (e < NEDGE) atomicAdd(&cdeg[dst[e]], 1);
}

// ---------- exclusive scan of cdeg -> rowstart (3 kernels) ----------
__global__ void k_scan1(const int* __restrict__ cdeg, int* __restrict__ rowstart,
                        int* __restrict__ bsum) {
    __shared__ int buf[256];
    int t = threadIdx.x;
    int i = blockIdx.x * 256 + t;
    int v = (i < NTOKEN) ? cdeg[i] : 0;
    buf[t] = v;
    __syncthreads();
    for (int off = 1; off < 256; off <<= 1) {
        int add = (t >= off) ? buf[t - off] : 0;
        __syncthreads();
        buf[t] += add;
        __syncthreads();
    }
    if (i < NTOKEN) rowstart[i] = buf[t] - v;   // exclusive within block
    if (t == 255) bsum[blockIdx.x] = buf[255];
}

__global__ void k_scan2(int* __restrict__ bsum) {
    __shared__ int buf[1024];
    int t = threadIdx.x;
    int v = (t < NB1) ? bsum[t] : 0;
    buf[t] = v;
    __syncthreads();
    for (int off = 1; off < 1024; off <<= 1) {
        int add = (t >= off) ? buf[t - off] : 0;
        __syncthreads();
        buf[t] += add;
        __syncthreads();
    }
    if (t < NB1) bsum[t] = buf[t] - v;          // exclusive block offsets
}

// rowstart += block offset; also dinv = rsqrt(deg+1)
__global__ void k_scan3(int* __restrict__ rowstart, const int* __restrict__ bsum,
                        const int* __restrict__ cdeg, float* __restrict__ dinv) {
    int i = blockIdx.x * blockDim.x + threadIdx.x;
    if (i < NTOKEN) {
        rowstart[i] += bsum[i >> 8];
        dinv[i] = rsqrtf((float)(cdeg[i] + 1));
    }
}

// ---------- counting-sort fill; rowstart mutates into end[] ----------
__global__ void k_fill(const int* __restrict__ src, const int* __restrict__ dst,
                       int* __restrict__ cursor, int* __restrict__ csr_src) {
    int e = blockIdx.x * blockDim.x + threadIdx.x;
    if (e < NEDGE) {
        int pos = atomicAdd(&cursor[dst[e]], 1);
        csr_src[pos] = src[e];
    }
}
// after k_fill: row i = [ (i ? end[i-1] : 0), end[i] )

// ---------- mark queried nodes ----------
__global__ void k_mark(const int* __restrict__ inp, unsigned char* __restrict__ mark) {
    int t = blockIdx.x * blockDim.x + threadIdx.x;
    if (t < NBL) mark[inp[t]] = 1;
}

// ---------- expand one hop: need2 = marked ∪ in-neighbors(marked) ----------
__global__ void k_need2(const unsigned char* __restrict__ mark, const int* __restrict__ end,
                        const int* __restrict__ csr_src, unsigned char* __restrict__ need2) {
    int i = blockIdx.x * blockDim.x + threadIdx.x;
    if (i >= NTOKEN || !mark[i]) return;
    need2[i] = 1;
    int b = (i > 0) ? end[i - 1] : 0;
    int f = end[i];
    for (int e = b; e < f; ++e) need2[csr_src[e]] = 1;
}

// ---------- layer 1 gather: P1[i] = A row i · emb  (needed nodes only) ----------
__global__ void k_gather1(const unsigned char* __restrict__ need2, const int* __restrict__ end,
                          const int* __restrict__ csr_src, const float* __restrict__ dinv,
                          const float* __restrict__ emb, float* __restrict__ P1) {
    int i = blockIdx.x * 4 + (threadIdx.x >> 6);
    if (i >= NTOKEN || !need2[i]) return;
    int lane = threadIdx.x & 63;
    float di = dinv[i];
    float acc = di * di * emb[i * NINP + lane];       // self loop
    int b = (i > 0) ? end[i - 1] : 0;
    int f = end[i];
    for (int e = b; e < f; ++e) {
        int s = csr_src[e];
        acc += dinv[s] * di * emb[s * NINP + lane];
    }
    P1[i * NINP + lane] = acc;
}

// ---------- fold weights: W12 = W1@W2 (64x64), bb = b1@W2 ----------
__global__ void k_w12(const float* __restrict__ W1, const float* __restrict__ W2,
                      const float* __restrict__ b1, float* __restrict__ W12,
                      float* __restrict__ bb) {
    int id = blockIdx.x * blockDim.x + threadIdx.x;
    if (id < 64 * 64) {
        int i = id >> 6, j = id & 63;
        float acc = 0.f;
        for (int k = 0; k < 128; ++k) acc += W1[i * 128 + k] * W2[k * 64 + j];
        W12[id] = acc;
    } else if (id < 64 * 64 + 64) {
        int j = id - 64 * 64;
        float acc = 0.f;
        for (int k = 0; k < 128; ++k) acc += b1[k] * W2[k * 64 + j];
        bb[j] = acc;
    }
}

// ---------- final: layer-2 gather + 64x64 GEMM + biases, one wave per token ----------
__global__ void k_final(const int* __restrict__ inp, const int* __restrict__ end,
                        const int* __restrict__ csr_src, const float* __restrict__ dinv,
                        const float* __restrict__ P1, const float* __restrict__ W12,
                        const float* __restrict__ bb, const float* __restrict__ b2,
                        float* __restrict__ out) {
    int t = blockIdx.x * 4 + (threadIdx.x >> 6);
    if (t >= NBL) return;
    int lane = threadIdx.x & 63;
    int n = inp[t];
    float dn = dinv[n];
    float p2 = dn * dn * P1[n * NINP + lane];         // self loop
    float sSum = dn;
    int b = (n > 0) ? end[n - 1] : 0;
    int f = end[n];
    for (int e = b; e < f; ++e) {
        int s = csr_src[e];
        float ds = dinv[s];
        p2 += ds * dn * P1[s * NINP + lane];
        sSum += ds;
    }
    float acc = b2[lane] + dn * sSum * bb[lane];
#pragma unroll
    for (int k = 0; k < 64; ++k)
        acc += __shfl(p2, k) * W12[k * 64 + lane];
    out[t * 64 + lane] = acc;
}

extern "C" void kernel_launch(void* const* d_in, const int* in_sizes, int n_in,
                              void* d_out, int out_size, void* d_ws, size_t ws_size,
                              hipStream_t stream) {
    const int*   inp  = (const int*)d_in[0];
    const int*   eidx = (const int*)d_in[3];
    const int*   esrc = eidx;
    const int*   edst = eidx + NEDGE;
    const float* emb  = (const float*)d_in[4];
    const float* W1   = (const float*)d_in[5];
    const float* b1   = (const float*)d_in[6];
    const float* W2   = (const float*)d_in[7];
    const float* b2   = (const float*)d_in[8];
    float* out = (float*)d_out;

    char* ws = (char*)d_ws;
    int*           cdeg     = (int*)(ws + 0);            //   800,000
    int*           rowstart = (int*)(ws + 800000);       //   800,000 (becomes end[])
    int*           bsum     = (int*)(ws + 1600000);      //     4,096
    float*         dinv     = (float*)(ws + 1604096);    //   800,000
    unsigned char* mark     = (unsigned char*)(ws + 2404096);  // 200,000
    unsigned char* need2    = (unsigned char*)(ws + 2604288);  // 200,000
    int*           csr_src  = (int*)(ws + 2804480);      // 8,000,000
    float*         W12      = (float*)(ws + 10804480);   //    16,384
    float*         bb       = (float*)(ws + 10820864);   //       256
    float*         P1       = (float*)(ws + 10821120);   // 51,200,000  (end ~62 MB)

    const int B = 256;

    k_init <<<NB1, B, 0, stream>>>(cdeg, mark, need2);
    k_count<<<(NEDGE + B - 1) / B, B, 0, stream>>>(edst, cdeg);
    k_scan1<<<NB1, B, 0, stream>>>(cdeg, rowstart, bsum);
    k_scan2<<<1, 1024, 0, stream>>>(bsum);
    k_scan3<<<NB1, B, 0, stream>>>(rowstart, bsum, cdeg, dinv);
    k_fill <<<(NEDGE + B - 1) / B, B, 0, stream>>>(esrc, edst, rowstart, csr_src);

    k_mark <<<(NBL + B - 1) / B, B, 0, stream>>>(inp, mark);
    k_need2<<<NB1, B, 0, stream>>>(mark, rowstart, csr_src, need2);

    k_gather1<<<(NTOKEN + 3) / 4, B, 0, stream>>>(need2, rowstart, csr_src, dinv, emb, P1);

    k_w12<<<(64 * 64 + 64 + B - 1) / B, B, 0, stream>>>(W1, W2, b1, W12, bb);
    k_final<<<(NBL + 3) / 4, B, 0, stream>>>(inp, rowstart, csr_src, dinv, P1, W12, bb, b2, out);
}

// Round 3
// 228.801 us; speedup vs baseline: 4.3521x; 1.7848x over previous
//
#include <hip/hip_runtime.h>

#define NTOKEN 200000
#define NINP   64
#define NEDGE  2000000
#define NBL    12800
#define NBKT   512
#define NPB    391            // nodes per bucket (511*391=199801; last bucket has 199)
#define CHUNK  4096
#define NCHUNK ((NEDGE + CHUNK - 1) / CHUNK)   // 489
#define CAP    6144           // per-bucket LDS staging capacity (mean 3906)

// ---- inclusive scan of s[0..511] with 256 threads; p is 256-int temp ----
__device__ __forceinline__ void scan512(int* s, int* p) {
    int t = threadIdx.x;
    int a = s[2 * t], b = s[2 * t + 1];
    p[t] = a + b;
    __syncthreads();
    for (int d = 1; d < 256; d <<= 1) {
        int v = (t >= d) ? p[t - d] : 0;
        __syncthreads();
        p[t] += v;
        __syncthreads();
    }
    int incl = p[t];
    s[2 * t + 1] = incl;
    s[2 * t]     = incl - b;
    __syncthreads();
}

__global__ void k_init(int* __restrict__ bCnt, unsigned char* __restrict__ mark,
                       unsigned char* __restrict__ need2) {
    int i = blockIdx.x * blockDim.x + threadIdx.x;
    if (i < NBKT) bCnt[i] = 0;
    if (i < NTOKEN) { mark[i] = 0; need2[i] = 0; }
}

// ---- pass A: bucket histogram, LDS pre-aggregated ----
__global__ void k_hist(const int* __restrict__ dst, int* __restrict__ bCnt) {
    __shared__ int h[NBKT];
    int t = threadIdx.x;
    h[t] = 0; h[t + 256] = 0;
    __syncthreads();
    for (int e = blockIdx.x * blockDim.x + t; e < NEDGE; e += gridDim.x * blockDim.x)
        atomicAdd(&h[(unsigned)dst[e] / NPB], 1);
    __syncthreads();
    if (h[t])       atomicAdd(&bCnt[t], h[t]);
    if (h[t + 256]) atomicAdd(&bCnt[t + 256], h[t + 256]);
}

// ---- pass S: scan bucket counts (1 block, 512 threads) ----
__global__ void k_scanB(const int* __restrict__ bCnt, int* __restrict__ bStart,
                        int* __restrict__ gCur) {
    __shared__ int buf[NBKT];
    int t = threadIdx.x;
    int v = bCnt[t];
    buf[t] = v;
    __syncthreads();
    for (int d = 1; d < NBKT; d <<= 1) {
        int add = (t >= d) ? buf[t - d] : 0;
        __syncthreads();
        buf[t] += add;
        __syncthreads();
    }
    bStart[t + 1] = buf[t];
    gCur[t] = buf[t] - v;     // exclusive
    if (t == 0) bStart[0] = 0;
}

// ---- pass B: chunked bucket scatter with coalesced writes ----
__global__ void k_bucket(const int* __restrict__ src, const int* __restrict__ dst,
                         int* __restrict__ gCur, int* __restrict__ E) {
    __shared__ int sv[CHUNK];   // packed values, bucket-sorted within chunk
    __shared__ int gd[CHUNK];   // global destination per slot
    __shared__ int h[NBKT];
    __shared__ int loff[NBKT];
    __shared__ int gb[NBKT];
    __shared__ int cur[NBKT];
    __shared__ int p[256];
    int t = threadIdx.x;
    int base = blockIdx.x * CHUNK;
    int cnt = NEDGE - base; if (cnt > CHUNK) cnt = CHUNK;

    h[t] = 0; h[t + 256] = 0; cur[t] = 0; cur[t + 256] = 0;
    __syncthreads();
    for (int j = t; j < cnt; j += 256)
        atomicAdd(&h[(unsigned)dst[base + j] / NPB], 1);
    __syncthreads();
    loff[2 * t] = h[2 * t]; loff[2 * t + 1] = h[2 * t + 1];
    __syncthreads();
    scan512(loff, p);                 // inclusive
    // reserve global space, convert loff to exclusive
    if (h[t])       gb[t]       = atomicAdd(&gCur[t],       h[t]);
    if (h[t + 256]) gb[t + 256] = atomicAdd(&gCur[t + 256], h[t + 256]);
    loff[t]       -= h[t];
    loff[t + 256] -= h[t + 256];
    __syncthreads();
    for (int j = t; j < cnt; j += 256) {
        unsigned d = (unsigned)dst[base + j];
        unsigned b = d / NPB;
        int packed = (int)(((d - b * NPB) << 18) | (unsigned)src[base + j]);
        int pl = atomicAdd(&cur[b], 1);
        int slot = loff[b] + pl;
        sv[slot] = packed;
        gd[slot] = gb[b] + pl;
    }
    __syncthreads();
    for (int j = t; j < cnt; j += 256)
        E[gd[j]] = sv[j];
}

// ---- pass C: per-bucket CSR build + deg/dinv/end, all writes coalesced ----
__global__ void k_csr(const int* __restrict__ E, const int* __restrict__ bStart,
                      int* __restrict__ csr, float* __restrict__ dinv,
                      int* __restrict__ endArr) {
    __shared__ int eL[CAP];
    __shared__ int csrL[CAP];
    __shared__ int cnt[NBKT];     // padded to 512 for scan
    __shared__ int off[NBKT];
    __shared__ int cur[NBKT];
    __shared__ int p[256];
    int t = threadIdx.x;
    int b = blockIdx.x;
    int base = bStart[b];
    int n = bStart[b + 1] - base;
    int nodes = NTOKEN - b * NPB; if (nodes > NPB) nodes = NPB;

    cnt[t] = 0; cnt[t + 256] = 0;
    __syncthreads();
    bool fits = (n <= CAP);
    if (fits) {
        for (int j = t; j < n; j += 256) {
            int v = E[base + j];
            eL[j] = v;
            atomicAdd(&cnt[v >> 18], 1);
        }
    } else {
        for (int j = t; j < n; j += 256)
            atomicAdd(&cnt[E[base + j] >> 18], 1);
    }
    __syncthreads();
    off[2 * t] = cnt[2 * t]; off[2 * t + 1] = cnt[2 * t + 1];
    __syncthreads();
    scan512(off, p);              // inclusive
    for (int i = t; i < nodes; i += 256) {
        dinv[b * NPB + i]  = rsqrtf((float)(cnt[i] + 1));
        endArr[b * NPB + i] = base + off[i];          // inclusive scan = row end
    }
    cur[t] = off[t] - cnt[t];
    cur[t + 256] = off[t + 256] - cnt[t + 256];
    __syncthreads();
    if (fits) {
        for (int j = t; j < n; j += 256) {
            int v = eL[j];
            int pos = atomicAdd(&cur[v >> 18], 1);
            csrL[pos] = v & 0x3FFFF;
        }
        __syncthreads();
        for (int j = t; j < n; j += 256)
            csr[base + j] = csrL[j];
    } else {
        for (int j = t; j < n; j += 256) {
            int v = E[base + j];
            int pos = atomicAdd(&cur[v >> 18], 1);
            csr[base + pos] = v & 0x3FFFF;
        }
    }
}

// ---- mark queried nodes ----
__global__ void k_mark(const int* __restrict__ inp, unsigned char* __restrict__ mark) {
    int t = blockIdx.x * blockDim.x + threadIdx.x;
    if (t < NBL) mark[inp[t]] = 1;
}

// ---- need2 = marked ∪ in-neighbors(marked) ----
__global__ void k_need2(const unsigned char* __restrict__ mark, const int* __restrict__ endArr,
                        const int* __restrict__ csr, unsigned char* __restrict__ need2) {
    int i = blockIdx.x * blockDim.x + threadIdx.x;
    if (i >= NTOKEN || !mark[i]) return;
    need2[i] = 1;
    int b = (i > 0) ? endArr[i - 1] : 0;
    int f = endArr[i];
    for (int e = b; e < f; ++e) need2[csr[e]] = 1;
}

// ---- layer 1 gather (needed nodes only) ----
__global__ void k_gather1(const unsigned char* __restrict__ need2, const int* __restrict__ endArr,
                          const int* __restrict__ csr, const float* __restrict__ dinv,
                          const float* __restrict__ emb, float* __restrict__ P1) {
    int i = blockIdx.x * 4 + (threadIdx.x >> 6);
    if (i >= NTOKEN || !need2[i]) return;
    int lane = threadIdx.x & 63;
    float di = dinv[i];
    float acc = di * di * emb[i * NINP + lane];
    int b = (i > 0) ? endArr[i - 1] : 0;
    int f = endArr[i];
    for (int e = b; e < f; ++e) {
        int s = csr[e];
        acc += dinv[s] * di * emb[s * NINP + lane];
    }
    P1[i * NINP + lane] = acc;
}

// ---- fold weights ----
__global__ void k_w12(const float* __restrict__ W1, const float* __restrict__ W2,
                      const float* __restrict__ b1, float* __restrict__ W12,
                      float* __restrict__ bb) {
    int id = blockIdx.x * blockDim.x + threadIdx.x;
    if (id < 64 * 64) {
        int i = id >> 6, j = id & 63;
        float acc = 0.f;
        for (int k = 0; k < 128; ++k) acc += W1[i * 128 + k] * W2[k * 64 + j];
        W12[id] = acc;
    } else if (id < 64 * 64 + 64) {
        int j = id - 64 * 64;
        float acc = 0.f;
        for (int k = 0; k < 128; ++k) acc += b1[k] * W2[k * 64 + j];
        bb[j] = acc;
    }
}

// ---- final: layer-2 gather + 64x64 GEMM + biases ----
__global__ void k_final(const int* __restrict__ inp, const int* __restrict__ endArr,
                        const int* __restrict__ csr, const float* __restrict__ dinv,
                        const float* __restrict__ P1, const float* __restrict__ W12,
                        const float* __restrict__ bb, const float* __restrict__ b2,
                        float* __restrict__ out) {
    int t = blockIdx.x * 4 + (threadIdx.x >> 6);
    if (t >= NBL) return;
    int lane = threadIdx.x & 63;
    int n = inp[t];
    float dn = dinv[n];
    float p2 = dn * dn * P1[n * NINP + lane];
    float sSum = dn;
    int b = (n > 0) ? endArr[n - 1] : 0;
    int f = endArr[n];
    for (int e = b; e < f; ++e) {
        int s = csr[e];
        float ds = dinv[s];
        p2 += ds * dn * P1[s * NINP + lane];
        sSum += ds;
    }
    float acc = b2[lane] + dn * sSum * bb[lane];
#pragma unroll
    for (int k = 0; k < 64; ++k)
        acc += __shfl(p2, k) * W12[k * 64 + lane];
    out[t * 64 + lane] = acc;
}

extern "C" void kernel_launch(void* const* d_in, const int* in_sizes, int n_in,
                              void* d_out, int out_size, void* d_ws, size_t ws_size,
                              hipStream_t stream) {
    const int*   inp  = (const int*)d_in[0];
    const int*   eidx = (const int*)d_in[3];
    const int*   esrc = eidx;
    const int*   edst = eidx + NEDGE;
    const float* emb  = (const float*)d_in[4];
    const float* W1   = (const float*)d_in[5];
    const float* b1   = (const float*)d_in[6];
    const float* W2   = (const float*)d_in[7];
    const float* b2   = (const float*)d_in[8];
    float* out = (float*)d_out;

    char* ws = (char*)d_ws;
    int*           bCnt   = (int*)(ws + 0);          // 2,048
    int*           bStart = (int*)(ws + 4096);       // 2,052
    int*           gCur   = (int*)(ws + 8192);       // 2,048
    float*         dinv   = (float*)(ws + 16384);    // 800,000
    int*           endArr = (int*)(ws + 817152);     // 800,000
    unsigned char* mark   = (unsigned char*)(ws + 1617408); // 200,000
    unsigned char* need2  = (unsigned char*)(ws + 1817600); // 200,000
    int*           E      = (int*)(ws + 2019328);    // 8,000,000
    int*           csr    = (int*)(ws + 10019328);   // 8,000,000
    float*         W12    = (float*)(ws + 18019328); // 16,384
    float*         bb     = (float*)(ws + 18035712); // 256
    float*         P1     = (float*)(ws + 18036224); // 51,200,000 (end ~69.2 MB)

    const int B = 256;

    k_init  <<<(NTOKEN + B - 1) / B, B, 0, stream>>>(bCnt, mark, need2);
    k_hist  <<<1024, B, 0, stream>>>(edst, bCnt);
    k_scanB <<<1, NBKT, 0, stream>>>(bCnt, bStart, gCur);
    k_bucket<<<NCHUNK, B, 0, stream>>>(esrc, edst, gCur, E);
    k_csr   <<<NBKT, B, 0, stream>>>(E, bStart, csr, dinv, endArr);

    k_mark  <<<(NBL + B - 1) / B, B, 0, stream>>>(inp, mark);
    k_need2 <<<(NTOKEN + B - 1) / B, B, 0, stream>>>(mark, endArr, csr, need2);

    k_gather1<<<(NTOKEN + 3) / 4, B, 0, stream>>>(need2, endArr, csr, dinv, emb, P1);

    k_w12   <<<(64 * 64 + 64 + B - 1) / B, B, 0, stream>>>(W1, W2, b1, W12, bb);
    k_final <<<(NBL + 3) / 4, B, 0, stream>>>(inp, endArr, csr, dinv, P1, W12, bb, b2, out);
}